// Round 4
// baseline (223.646 us; speedup 1.0000x reference)
//
#include <hip/hip_runtime.h>

#define BN 4
#define NN 8192
#define EE 128
#define HH 4
#define DD 32
#define WW 33
#define MROWS (BN*NN)            // 32768
#define QELEMS (MROWS*EE)        // 4194304
#define WELEMS (EE*EE)           // 16384

typedef __bf16 bf16x8 __attribute__((ext_vector_type(8)));
typedef float f32x4 __attribute__((ext_vector_type(4)));
typedef unsigned short u16x8 __attribute__((ext_vector_type(8)));

static __device__ __forceinline__ unsigned short f2bf(float x){
    unsigned u = __float_as_uint(x);
    u += 0x7fffu + ((u >> 16) & 1u);
    return (unsigned short)(u >> 16);
}
static __device__ __forceinline__ float bf2f(unsigned short h){
    return __uint_as_float(((unsigned)h) << 16);
}
static __device__ __forceinline__ bf16x8 ld_bf8(const unsigned short* p){
    u16x8 v = *(const u16x8*)p;
    return __builtin_bit_cast(bf16x8, v);
}

// ---------------- prep: weights fp32 -> bf16 hi/lo ----------------
__global__ void __launch_bounds__(256) prep_w(const float* __restrict__ wq, const float* __restrict__ wk,
        const float* __restrict__ wv, const float* __restrict__ wo,
        unsigned short* __restrict__ wh, unsigned short* __restrict__ wl){
    int i = blockIdx.x*256 + threadIdx.x;       // 0..65535
    int sel = i >> 14;
    const float* src = (sel==0)? wq : (sel==1)? wk : (sel==2)? wv : wo;
    float x = src[i & (WELEMS-1)];
    unsigned short h = f2bf(x);
    wh[i] = h;
    wl[i] = f2bf(x - bf2f(h));
}

// ---------------- QKV projection ----------------
// Block = 4 waves = 16 rows x 128 cols of ONE projection (blockIdx.y).
// Wave wid covers col-tiles {2*wid, 2*wid+1}. grid (2048, 3) for occupancy.
__global__ void __launch_bounds__(256) gemm_qkv(const float* __restrict__ q,
        const unsigned short* __restrict__ wh, const unsigned short* __restrict__ wl,
        const float* __restrict__ bq, const float* __restrict__ bk, const float* __restrict__ bv_,
        float* __restrict__ Qf, float* __restrict__ Kf, float* __restrict__ Vf)
{
    const int wid = threadIdx.x >> 6;
    const int lane = threadIdx.x & 63;
    const int m = lane & 15, g = lane >> 4;
    const int row0 = blockIdx.x * 16;
    const int p = blockIdx.y;

    // A fragments: row (row0+m), k = kc*32 + g*8 .. +8, split f32 -> hi/lo bf16
    bf16x8 aH[4], aL[4];
    const float* qrow = q + (size_t)(row0 + m) * EE;
    #pragma unroll
    for (int kc=0;kc<4;kc++){
        float4 v0 = *(const float4*)(qrow + kc*32 + g*8);
        float4 v1 = *(const float4*)(qrow + kc*32 + g*8 + 4);
        float vv[8] = {v0.x,v0.y,v0.z,v0.w,v1.x,v1.y,v1.z,v1.w};
        u16x8 hh, ll;
        #pragma unroll
        for (int j=0;j<8;j++){
            unsigned short h = f2bf(vv[j]);
            hh[j] = h;
            ll[j] = f2bf(vv[j] - bf2f(h));
        }
        aH[kc] = __builtin_bit_cast(bf16x8, hh);
        aL[kc] = __builtin_bit_cast(bf16x8, ll);
    }

    const unsigned short* WH = wh + p*WELEMS;
    const unsigned short* WL = wl + p*WELEMS;
    const float* bias = (p==0)? bq : (p==1)? bk : bv_;
    float* out = (p==0)? Qf : (p==1)? Kf : Vf;

    #pragma unroll
    for (int cti=0; cti<2; cti++){
        const int col0 = (wid*2 + cti)*16;
        const size_t wbase = (size_t)(col0 + m) * EE;
        f32x4 acc = {0.f,0.f,0.f,0.f};
        #pragma unroll
        for (int kc=0;kc<4;kc++){
            bf16x8 bH = ld_bf8(WH + wbase + kc*32 + g*8);
            bf16x8 bL = ld_bf8(WL + wbase + kc*32 + g*8);
            acc = __builtin_amdgcn_mfma_f32_16x16x32_bf16(aH[kc], bH, acc, 0,0,0);
            acc = __builtin_amdgcn_mfma_f32_16x16x32_bf16(aH[kc], bL, acc, 0,0,0);
            acc = __builtin_amdgcn_mfma_f32_16x16x32_bf16(aL[kc], bH, acc, 0,0,0);
        }
        const float bv = bias[col0 + m];
        #pragma unroll
        for (int r=0;r<4;r++){
            int row = row0 + g*4 + r;          // D: col = lane&15, row = g*4 + r
            out[(size_t)row*EE + col0 + m] = acc[r] + bv;
        }
    }
}

// ---------------- output projection (A = attn out, bf16 hi/lo in ws) ----------------
__global__ void __launch_bounds__(256) gemm_o(const unsigned short* __restrict__ ah,
        const unsigned short* __restrict__ al,
        const unsigned short* __restrict__ WH, const unsigned short* __restrict__ WL,
        const float* __restrict__ bo, float* __restrict__ out)
{
    const int wid = threadIdx.x >> 6;
    const int lane = threadIdx.x & 63;
    const int m = lane & 15, g = lane >> 4;
    const int row0 = blockIdx.x * 16;

    bf16x8 aH[4], aL[4];
    const size_t abase = (size_t)(row0 + m) * EE;
    #pragma unroll
    for (int kc=0;kc<4;kc++){
        aH[kc] = ld_bf8(ah + abase + kc*32 + g*8);
        aL[kc] = ld_bf8(al + abase + kc*32 + g*8);
    }
    #pragma unroll
    for (int cti=0; cti<2; cti++){
        const int col0 = (wid*2 + cti)*16;
        const size_t wbase = (size_t)(col0 + m) * EE;
        f32x4 acc = {0.f,0.f,0.f,0.f};
        #pragma unroll
        for (int kc=0;kc<4;kc++){
            bf16x8 bH = ld_bf8(WH + wbase + kc*32 + g*8);
            bf16x8 bL = ld_bf8(WL + wbase + kc*32 + g*8);
            acc = __builtin_amdgcn_mfma_f32_16x16x32_bf16(aH[kc], bH, acc, 0,0,0);
            acc = __builtin_amdgcn_mfma_f32_16x16x32_bf16(aH[kc], bL, acc, 0,0,0);
            acc = __builtin_amdgcn_mfma_f32_16x16x32_bf16(aL[kc], bH, acc, 0,0,0);
        }
        const float bv = bo[col0 + m];
        #pragma unroll
        for (int r=0;r<4;r++){
            int row = row0 + g*4 + r;
            out[(size_t)row*EE + col0 + m] = acc[r] + bv;
        }
    }
}

// ---------------- sliding-window attention, fp32 exact ----------------
// 4 threads per position (each owns 8 of D=32). Block = 256 thr = 64 positions
// of one (b,h). LDS: 96-row halo, stride 33 (bank-shift +1 per row), 25.3 KB.
__global__ void __launch_bounds__(256) attn_kernel(const float* __restrict__ Qf,
        const float* __restrict__ Kf, const float* __restrict__ Vf,
        float* __restrict__ probs, unsigned short* __restrict__ ah, unsigned short* __restrict__ al)
{
    __shared__ float Kl[96*33];
    __shared__ float Vl[96*33];
    const int t = threadIdx.x;
    const int bh = blockIdx.y;
    const int b = bh >> 2, h = bh & 3;
    const int n0 = blockIdx.x * 64;
    const size_t rowbase = (size_t)b * NN;

    // stage K/V rows [n0-16, n0+80) slice [h*32, h*32+32), zero-fill OOB
    #pragma unroll
    for (int i=0;i<3;i++){
        int idx = t + i*256;                   // 0..767
        int row = idx >> 3, q4 = idx & 7;
        int grow = n0 - 16 + row;
        float4 kv = make_float4(0.f,0.f,0.f,0.f);
        float4 vv = make_float4(0.f,0.f,0.f,0.f);
        if (grow >= 0 && grow < NN){
            size_t goff = (rowbase + grow)*EE + h*DD + q4*4;
            kv = *(const float4*)(Kf + goff);
            vv = *(const float4*)(Vf + goff);
        }
        int lo = row*33 + q4*4;
        *(float4*)(Kl + lo) = kv;
        *(float4*)(Vl + lo) = vv;
    }
    __syncthreads();

    const int p = t >> 2, e = t & 3;           // position p, dim-quarter e
    const int n = n0 + p;

    float qr[8];
    {
        const float4* qp = (const float4*)(Qf + (rowbase + n)*EE + h*DD + e*8);
        float4 v0 = qp[0], v1 = qp[1];
        qr[0]=v0.x; qr[1]=v0.y; qr[2]=v0.z; qr[3]=v0.w;
        qr[4]=v1.x; qr[5]=v1.y; qr[6]=v1.z; qr[7]=v1.w;
    }

    float sc[WW];
    #pragma unroll
    for (int w=0; w<WW; w++){
        const float* kr = &Kl[(p+w)*33 + e*8];
        float s = 0.f;
        #pragma unroll
        for (int k=0;k<8;k++) s = fmaf(qr[k], kr[k], s);
        sc[w] = s;
    }
    // quad-reduce: all 4 threads end with the full dot product
    #pragma unroll
    for (int w=0; w<WW; w++){
        float s = sc[w];
        s += __shfl_xor(s, 1);
        s += __shfl_xor(s, 2);
        sc[w] = s * 0.17677669529663687f;      // 1/sqrt(32)
    }

    float mx = sc[0];
    #pragma unroll
    for (int w=1;w<WW;w++) mx = fmaxf(mx, sc[w]);
    float sum = 0.f;
    #pragma unroll
    for (int w=0;w<WW;w++){ sc[w] = __expf(sc[w]-mx); sum += sc[w]; }
    float inv = 1.f / sum;
    #pragma unroll
    for (int w=0;w<WW;w++) sc[w] *= inv;

    // probs: quad splits the 33 writes (9+8+8+8)
    float* pp = probs + ((size_t)bh*NN + n)*WW;
    {
        int w0 = (e==0)? 0 : 9 + (e-1)*8;
        int w1 = (e==0)? 9 : w0 + 8;
        for (int w=w0; w<w1; w++) pp[w] = sc[w];
    }

    // PV over own 8 dims
    float acc[8];
    #pragma unroll
    for (int k=0;k<8;k++) acc[k]=0.f;
    #pragma unroll
    for (int w=0;w<WW;w++){
        const float* vr = &Vl[(p+w)*33 + e*8];
        float pw = sc[w];
        #pragma unroll
        for (int k=0;k<8;k++) acc[k] = fmaf(pw, vr[k], acc[k]);
    }

    unsigned short hi[8], lo2[8];
    #pragma unroll
    for (int k=0;k<8;k++){ hi[k]=f2bf(acc[k]); lo2[k]=f2bf(acc[k]-bf2f(hi[k])); }
    size_t aoff = (rowbase + n)*EE + h*DD + e*8;
    *(ushort4*)(ah + aoff)     = make_ushort4(hi[0],hi[1],hi[2],hi[3]);
    *(ushort4*)(ah + aoff + 4) = make_ushort4(hi[4],hi[5],hi[6],hi[7]);
    *(ushort4*)(al + aoff)     = make_ushort4(lo2[0],lo2[1],lo2[2],lo2[3]);
    *(ushort4*)(al + aoff + 4) = make_ushort4(lo2[4],lo2[5],lo2[6],lo2[7]);
}

extern "C" void kernel_launch(void* const* d_in, const int* in_sizes, int n_in,
                              void* d_out, int out_size, void* d_ws, size_t ws_size,
                              hipStream_t stream) {
    const float* q  = (const float*)d_in[0];
    const float* Wq = (const float*)d_in[1];  const float* bq = (const float*)d_in[2];
    const float* Wk = (const float*)d_in[3];  const float* bk = (const float*)d_in[4];
    const float* Wv = (const float*)d_in[5];  const float* bv = (const float*)d_in[6];
    const float* Wo = (const float*)d_in[7];  const float* bo = (const float*)d_in[8];

    float* out   = (float*)d_out;             // (B,N,E) = 4194304 floats
    float* probs = out + QELEMS;              // (B,H,N,W) = 4325376 floats

    // workspace carve (~67 MB)
    unsigned short* a_hi = (unsigned short*)d_ws;
    unsigned short* a_lo = a_hi + QELEMS;
    unsigned short* w_hi = a_lo + QELEMS;
    unsigned short* w_lo = w_hi + 4*WELEMS;
    float* Qf = (float*)(w_lo + 4*WELEMS);
    float* Kf = Qf + QELEMS;
    float* Vf = Kf + QELEMS;

    prep_w<<<4*WELEMS/256, 256, 0, stream>>>(Wq, Wk, Wv, Wo, w_hi, w_lo);
    gemm_qkv<<<dim3(MROWS/16, 3), 256, 0, stream>>>(q, w_hi, w_lo,
                                                    bq, bk, bv, Qf, Kf, Vf);
    attn_kernel<<<dim3(NN/64, BN*HH), 256, 0, stream>>>(Qf, Kf, Vf, probs, a_hi, a_lo);
    gemm_o<<<dim3(MROWS/16, 1), 256, 0, stream>>>(a_hi, a_lo,
                                                  w_hi + 3*WELEMS, w_lo + 3*WELEMS, bo, out);
}

// Round 6
// 185.210 us; speedup vs baseline: 1.2075x; 1.2075x over previous
//
#include <hip/hip_runtime.h>

#define BN 4
#define NN 8192
#define EE 128
#define HH 4
#define DD 32
#define WW 33
#define MROWS (BN*NN)            // 32768
#define QELEMS (MROWS*EE)        // 4194304
#define WELEMS (EE*EE)           // 16384

typedef __bf16 bf16x8 __attribute__((ext_vector_type(8)));
typedef float f32x4 __attribute__((ext_vector_type(4)));
typedef unsigned short u16x8 __attribute__((ext_vector_type(8)));

static __device__ __forceinline__ unsigned short f2bf(float x){
    unsigned u = __float_as_uint(x);
    u += 0x7fffu + ((u >> 16) & 1u);
    return (unsigned short)(u >> 16);
}
static __device__ __forceinline__ float bf2f(unsigned short h){
    return __uint_as_float(((unsigned)h) << 16);
}
static __device__ __forceinline__ bf16x8 ld_bf8(const unsigned short* p){
    u16x8 v = *(const u16x8*)p;
    return __builtin_bit_cast(bf16x8, v);
}

// ---------------- prep: weights fp32 -> bf16 hi/lo ----------------
__global__ void __launch_bounds__(256) prep_w(const float* __restrict__ wq, const float* __restrict__ wk,
        const float* __restrict__ wv, const float* __restrict__ wo,
        unsigned short* __restrict__ wh, unsigned short* __restrict__ wl){
    int i = blockIdx.x*256 + threadIdx.x;       // 0..65535
    int sel = i >> 14;
    const float* src = (sel==0)? wq : (sel==1)? wk : (sel==2)? wv : wo;
    float x = src[i & (WELEMS-1)];
    unsigned short h = f2bf(x);
    wh[i] = h;
    wl[i] = f2bf(x - bf2f(h));
}

// ---------------- QKV projection ----------------
// Block = 4 waves = 64 rows x 64 cols x ALL 3 projections (A-split amortized
// over 144 MFMAs/wave). grid (512, 2 col-halves) = 1024 blocks.
__global__ void __launch_bounds__(256,4) gemm_qkv(const float* __restrict__ q,
        const unsigned short* __restrict__ wh, const unsigned short* __restrict__ wl,
        const float* __restrict__ bq, const float* __restrict__ bk, const float* __restrict__ bv_,
        float* __restrict__ Qf, float* __restrict__ Kf, float* __restrict__ Vf)
{
    const int wid = threadIdx.x >> 6;
    const int lane = threadIdx.x & 63;
    const int m = lane & 15, g = lane >> 4;
    const int row0 = blockIdx.x*64 + wid*16;
    const int ch = blockIdx.y;                 // column half: cols [ch*64, ch*64+64)

    // A fragments: row (row0+m), k = kc*32 + g*8 .. +8, split f32 -> hi/lo bf16
    bf16x8 aH[4], aL[4];
    const float* qrow = q + (size_t)(row0 + m) * EE;
    #pragma unroll
    for (int kc=0;kc<4;kc++){
        float4 v0 = *(const float4*)(qrow + kc*32 + g*8);
        float4 v1 = *(const float4*)(qrow + kc*32 + g*8 + 4);
        float vv[8] = {v0.x,v0.y,v0.z,v0.w,v1.x,v1.y,v1.z,v1.w};
        u16x8 hh, ll;
        #pragma unroll
        for (int j=0;j<8;j++){
            unsigned short h = f2bf(vv[j]);
            hh[j] = h;
            ll[j] = f2bf(vv[j] - bf2f(h));
        }
        aH[kc] = __builtin_bit_cast(bf16x8, hh);
        aL[kc] = __builtin_bit_cast(bf16x8, ll);
    }

    const float* biases[3] = {bq, bk, bv_};
    float* outs[3] = {Qf, Kf, Vf};
    #pragma unroll
    for (int p=0;p<3;p++){
        const unsigned short* WH = wh + p*WELEMS;
        const unsigned short* WL = wl + p*WELEMS;
        const float* bias = biases[p];
        float* out = outs[p];
        #pragma unroll
        for (int cti=0; cti<4; cti++){
            const int col0 = (ch*4 + cti)*16;
            const size_t wbase = (size_t)(col0 + m) * EE;
            f32x4 acc = {0.f,0.f,0.f,0.f};
            #pragma unroll
            for (int kc=0;kc<4;kc++){
                bf16x8 bH = ld_bf8(WH + wbase + kc*32 + g*8);
                bf16x8 bL = ld_bf8(WL + wbase + kc*32 + g*8);
                acc = __builtin_amdgcn_mfma_f32_16x16x32_bf16(aH[kc], bH, acc, 0,0,0);
                acc = __builtin_amdgcn_mfma_f32_16x16x32_bf16(aH[kc], bL, acc, 0,0,0);
                acc = __builtin_amdgcn_mfma_f32_16x16x32_bf16(aL[kc], bH, acc, 0,0,0);
            }
            const float bv = bias[col0 + m];
            #pragma unroll
            for (int r=0;r<4;r++){
                int row = row0 + g*4 + r;          // D: col = lane&15, row = g*4 + r
                out[(size_t)row*EE + col0 + m] = acc[r] + bv;
            }
        }
    }
}

// ---------------- output projection (A = attn out, bf16 hi/lo in ws) ----------------
// Block = 64 rows x 64 cols. grid (512, 2).
__global__ void __launch_bounds__(256,4) gemm_o(const unsigned short* __restrict__ ah,
        const unsigned short* __restrict__ al,
        const unsigned short* __restrict__ WH, const unsigned short* __restrict__ WL,
        const float* __restrict__ bo, float* __restrict__ out)
{
    const int wid = threadIdx.x >> 6;
    const int lane = threadIdx.x & 63;
    const int m = lane & 15, g = lane >> 4;
    const int row0 = blockIdx.x*64 + wid*16;
    const int ch = blockIdx.y;

    bf16x8 aH[4], aL[4];
    const size_t abase = (size_t)(row0 + m) * EE;
    #pragma unroll
    for (int kc=0;kc<4;kc++){
        aH[kc] = ld_bf8(ah + abase + kc*32 + g*8);
        aL[kc] = ld_bf8(al + abase + kc*32 + g*8);
    }
    #pragma unroll
    for (int cti=0; cti<4; cti++){
        const int col0 = (ch*4 + cti)*16;
        const size_t wbase = (size_t)(col0 + m) * EE;
        f32x4 acc = {0.f,0.f,0.f,0.f};
        #pragma unroll
        for (int kc=0;kc<4;kc++){
            bf16x8 bH = ld_bf8(WH + wbase + kc*32 + g*8);
            bf16x8 bL = ld_bf8(WL + wbase + kc*32 + g*8);
            acc = __builtin_amdgcn_mfma_f32_16x16x32_bf16(aH[kc], bH, acc, 0,0,0);
            acc = __builtin_amdgcn_mfma_f32_16x16x32_bf16(aH[kc], bL, acc, 0,0,0);
            acc = __builtin_amdgcn_mfma_f32_16x16x32_bf16(aL[kc], bH, acc, 0,0,0);
        }
        const float bv = bo[col0 + m];
        #pragma unroll
        for (int r=0;r<4;r++){
            int row = row0 + g*4 + r;
            out[(size_t)row*EE + col0 + m] = acc[r] + bv;
        }
    }
}

// ---------------- sliding-window attention, fp32 exact ----------------
// 4 threads per position (each owns 8 of D=32). Block = 256 thr = 64 positions
// of one (b,h). LDS: K/V 96-row halo stride 33 + probs staging. ~33 KB.
// ALL sc[] indexing is compile-time (rule #20: runtime index -> scratch spill).
__global__ void __launch_bounds__(256) attn_kernel(const float* __restrict__ Qf,
        const float* __restrict__ Kf, const float* __restrict__ Vf,
        float* __restrict__ probs, unsigned short* __restrict__ ah, unsigned short* __restrict__ al)
{
    __shared__ float Kl[96*33];
    __shared__ float Vl[96*33];
    __shared__ float Pl[64*WW];                // probs staging, 64 rows x 33
    const int t = threadIdx.x;
    const int bh = blockIdx.y;
    const int b = bh >> 2, h = bh & 3;
    const int n0 = blockIdx.x * 64;
    const size_t rowbase = (size_t)b * NN;

    // stage K/V rows [n0-16, n0+80) slice [h*32, h*32+32), zero-fill OOB
    #pragma unroll
    for (int i=0;i<3;i++){
        int idx = t + i*256;                   // 0..767
        int row = idx >> 3, q4 = idx & 7;
        int grow = n0 - 16 + row;
        float4 kv = make_float4(0.f,0.f,0.f,0.f);
        float4 vv = make_float4(0.f,0.f,0.f,0.f);
        if (grow >= 0 && grow < NN){
            size_t goff = (rowbase + grow)*EE + h*DD + q4*4;
            kv = *(const float4*)(Kf + goff);
            vv = *(const float4*)(Vf + goff);
        }
        int lo = row*33 + q4*4;
        *(float4*)(Kl + lo) = kv;
        *(float4*)(Vl + lo) = vv;
    }
    __syncthreads();

    const int p = t >> 2, e = t & 3;           // position p, dim-quarter e
    const int n = n0 + p;

    float qr[8];
    {
        const float4* qp = (const float4*)(Qf + (rowbase + n)*EE + h*DD + e*8);
        float4 v0 = qp[0], v1 = qp[1];
        qr[0]=v0.x; qr[1]=v0.y; qr[2]=v0.z; qr[3]=v0.w;
        qr[4]=v1.x; qr[5]=v1.y; qr[6]=v1.z; qr[7]=v1.w;
    }

    float sc[WW];
    #pragma unroll
    for (int w=0; w<WW; w++){
        const float* kr = &Kl[(p+w)*33 + e*8];
        float s = 0.f;
        #pragma unroll
        for (int k=0;k<8;k++) s = fmaf(qr[k], kr[k], s);
        sc[w] = s;
    }
    // quad-reduce: all 4 threads end with the full dot product
    #pragma unroll
    for (int w=0; w<WW; w++){
        float s = sc[w];
        s += __shfl_xor(s, 1);
        s += __shfl_xor(s, 2);
        sc[w] = s * 0.17677669529663687f;      // 1/sqrt(32)
    }

    float mx = sc[0];
    #pragma unroll
    for (int w=1;w<WW;w++) mx = fmaxf(mx, sc[w]);
    float sum = 0.f;
    #pragma unroll
    for (int w=0;w<WW;w++){ sc[w] = __expf(sc[w]-mx); sum += sc[w]; }
    float inv = 1.f / sum;
    #pragma unroll
    for (int w=0;w<WW;w++) sc[w] *= inv;

    // probs -> LDS staging; quad splits 9+8+8+8, every sc[] index compile-time
    {
        float* pl = Pl + p*WW;
        if (e==0){
            #pragma unroll
            for (int w=0;w<9;w++) pl[w] = sc[w];
        } else if (e==1){
            #pragma unroll
            for (int w=9;w<17;w++) pl[w] = sc[w];
        } else if (e==2){
            #pragma unroll
            for (int w=17;w<25;w++) pl[w] = sc[w];
        } else {
            #pragma unroll
            for (int w=25;w<WW;w++) pl[w] = sc[w];
        }
    }

    // PV over own 8 dims
    float acc[8];
    #pragma unroll
    for (int k=0;k<8;k++) acc[k]=0.f;
    #pragma unroll
    for (int w=0;w<WW;w++){
        const float* vr = &Vl[(p+w)*33 + e*8];
        float pw = sc[w];
        #pragma unroll
        for (int k=0;k<8;k++) acc[k] = fmaf(pw, vr[k], acc[k]);
    }

    unsigned short hi[8], lo2[8];
    #pragma unroll
    for (int k=0;k<8;k++){ hi[k]=f2bf(acc[k]); lo2[k]=f2bf(acc[k]-bf2f(hi[k])); }
    size_t aoff = (rowbase + n)*EE + h*DD + e*8;
    *(ushort4*)(ah + aoff)     = make_ushort4(hi[0],hi[1],hi[2],hi[3]);
    *(ushort4*)(ah + aoff + 4) = make_ushort4(hi[4],hi[5],hi[6],hi[7]);
    *(ushort4*)(al + aoff)     = make_ushort4(lo2[0],lo2[1],lo2[2],lo2[3]);
    *(ushort4*)(al + aoff + 4) = make_ushort4(lo2[4],lo2[5],lo2[6],lo2[7]);

    // coalesced probs flush: block's region is 64*33 = 2112 contiguous floats
    __syncthreads();
    float* pbase = probs + ((size_t)bh*NN + n0)*WW;
    #pragma unroll
    for (int i=0;i<9;i++){
        int idx = t + i*256;
        if (idx < 64*WW) pbase[idx] = Pl[idx];
    }
}

extern "C" void kernel_launch(void* const* d_in, const int* in_sizes, int n_in,
                              void* d_out, int out_size, void* d_ws, size_t ws_size,
                              hipStream_t stream) {
    const float* q  = (const float*)d_in[0];
    const float* Wq = (const float*)d_in[1];  const float* bq = (const float*)d_in[2];
    const float* Wk = (const float*)d_in[3];  const float* bk = (const float*)d_in[4];
    const float* Wv = (const float*)d_in[5];  const float* bv = (const float*)d_in[6];
    const float* Wo = (const float*)d_in[7];  const float* bo = (const float*)d_in[8];

    float* out   = (float*)d_out;             // (B,N,E) = 4194304 floats
    float* probs = out + QELEMS;              // (B,H,N,W) = 4325376 floats

    // workspace carve (~67 MB)
    unsigned short* a_hi = (unsigned short*)d_ws;
    unsigned short* a_lo = a_hi + QELEMS;
    unsigned short* w_hi = a_lo + QELEMS;
    unsigned short* w_lo = w_hi + 4*WELEMS;
    float* Qf = (float*)(w_lo + 4*WELEMS);
    float* Kf = Qf + QELEMS;
    float* Vf = Kf + QELEMS;

    prep_w<<<4*WELEMS/256, 256, 0, stream>>>(Wq, Wk, Wv, Wo, w_hi, w_lo);
    gemm_qkv<<<dim3(MROWS/64, 2), 256, 0, stream>>>(q, w_hi, w_lo,
                                                    bq, bk, bv, Qf, Kf, Vf);
    attn_kernel<<<dim3(NN/64, BN*HH), 256, 0, stream>>>(Qf, Kf, Vf, probs, a_hi, a_lo);
    gemm_o<<<dim3(MROWS/64, 2), 256, 0, stream>>>(a_hi, a_lo,
                                                  w_hi + 3*WELEMS, w_lo + 3*WELEMS, bo, out);
}

// Round 7
// 161.746 us; speedup vs baseline: 1.3827x; 1.1451x over previous
//
#include <hip/hip_runtime.h>

#define BN 4
#define NN 8192
#define EE 128
#define HH 4
#define DD 32
#define WW 33
#define MROWS (BN*NN)            // 32768
#define QELEMS (MROWS*EE)        // 4194304
#define WELEMS (EE*EE)           // 16384
#define RT 8                     // row-tiles (of 16 rows) per GEMM block

typedef __bf16 bf16x8 __attribute__((ext_vector_type(8)));
typedef float f32x4 __attribute__((ext_vector_type(4)));
typedef unsigned short u16x8 __attribute__((ext_vector_type(8)));

static __device__ __forceinline__ unsigned short f2bf(float x){
    unsigned u = __float_as_uint(x);
    u += 0x7fffu + ((u >> 16) & 1u);
    return (unsigned short)(u >> 16);
}
static __device__ __forceinline__ float bf2f(unsigned short h){
    return __uint_as_float(((unsigned)h) << 16);
}
static __device__ __forceinline__ bf16x8 ld_bf8(const unsigned short* p){
    u16x8 v = *(const u16x8*)p;
    return __builtin_bit_cast(bf16x8, v);
}

// ---------------- prep: weights fp32 -> bf16 hi/lo ----------------
__global__ void __launch_bounds__(256) prep_w(const float* __restrict__ wq, const float* __restrict__ wk,
        const float* __restrict__ wv, const float* __restrict__ wo,
        unsigned short* __restrict__ wh, unsigned short* __restrict__ wl){
    int i = blockIdx.x*256 + threadIdx.x;       // 0..65535
    int sel = i >> 14;
    const float* src = (sel==0)? wq : (sel==1)? wk : (sel==2)? wv : wo;
    float x = src[i & (WELEMS-1)];
    unsigned short h = f2bf(x);
    wh[i] = h;
    wl[i] = f2bf(x - bf2f(h));
}

// ---------------- QKV projection: weights in registers, stream A ----------------
// Block = 512 thr = 8 waves. Wave w holds B-frags (hi+lo) for ALL 3 projections
// at cols [w*16, w*16+16) -> 96 VGPR, loaded once. Loop over RT row-tiles of A,
// double-buffered raw-f32 loads (compile-time indices only), split in-reg.
__global__ void __launch_bounds__(512,2) gemm_qkv(const float* __restrict__ q,
        const unsigned short* __restrict__ wh, const unsigned short* __restrict__ wl,
        const float* __restrict__ bq, const float* __restrict__ bk, const float* __restrict__ bv_,
        float* __restrict__ Qf, float* __restrict__ Kf, float* __restrict__ Vf)
{
    const int w = threadIdx.x >> 6;            // wave id 0..7 -> col-tile w*16
    const int lane = threadIdx.x & 63;
    const int m = lane & 15, g = lane >> 4;
    const int rowB = blockIdx.x * (16*RT);

    // B fragments: proj i, row (w*16+m) of W, k = kc*32+g*8
    bf16x8 bH[3][4], bL[3][4];
    #pragma unroll
    for (int i=0;i<3;i++){
        const unsigned short* WHp = wh + i*WELEMS + (size_t)(w*16 + m)*EE;
        const unsigned short* WLp = wl + i*WELEMS + (size_t)(w*16 + m)*EE;
        #pragma unroll
        for (int kc=0;kc<4;kc++){
            bH[i][kc] = ld_bf8(WHp + kc*32 + g*8);
            bL[i][kc] = ld_bf8(WLp + kc*32 + g*8);
        }
    }
    const float bias[3] = { bq[w*16+m], bk[w*16+m], bv_[w*16+m] };
    float* const outp[3] = { Qf, Kf, Vf };

    float4 fa[2][8];                            // [buf][kc*2+half] raw f32 A
    {
        const float* qrow = q + (size_t)(rowB + m) * EE;
        #pragma unroll
        for (int kc=0;kc<4;kc++){
            fa[0][kc*2]   = *(const float4*)(qrow + kc*32 + g*8);
            fa[0][kc*2+1] = *(const float4*)(qrow + kc*32 + g*8 + 4);
        }
    }
    #pragma unroll
    for (int rt=0; rt<RT; rt++){
        const int row0 = rowB + rt*16;
        if (rt+1 < RT){                         // prefetch next tile
            const float* qrow = q + (size_t)(row0 + 16 + m) * EE;
            #pragma unroll
            for (int kc=0;kc<4;kc++){
                fa[(rt+1)&1][kc*2]   = *(const float4*)(qrow + kc*32 + g*8);
                fa[(rt+1)&1][kc*2+1] = *(const float4*)(qrow + kc*32 + g*8 + 4);
            }
        }
        bf16x8 aH[4], aL[4];
        #pragma unroll
        for (int kc=0;kc<4;kc++){
            float4 v0 = fa[rt&1][kc*2], v1 = fa[rt&1][kc*2+1];
            float vv[8] = {v0.x,v0.y,v0.z,v0.w,v1.x,v1.y,v1.z,v1.w};
            u16x8 hh, ll;
            #pragma unroll
            for (int j=0;j<8;j++){
                unsigned short h = f2bf(vv[j]);
                hh[j] = h;
                ll[j] = f2bf(vv[j] - bf2f(h));
            }
            aH[kc] = __builtin_bit_cast(bf16x8, hh);
            aL[kc] = __builtin_bit_cast(bf16x8, ll);
        }
        #pragma unroll
        for (int i=0;i<3;i++){
            f32x4 acc = {0.f,0.f,0.f,0.f};
            #pragma unroll
            for (int kc=0;kc<4;kc++){
                acc = __builtin_amdgcn_mfma_f32_16x16x32_bf16(aH[kc], bH[i][kc], acc, 0,0,0);
                acc = __builtin_amdgcn_mfma_f32_16x16x32_bf16(aH[kc], bL[i][kc], acc, 0,0,0);
                acc = __builtin_amdgcn_mfma_f32_16x16x32_bf16(aL[kc], bH[i][kc], acc, 0,0,0);
            }
            float* op = outp[i] + (size_t)(row0 + g*4)*EE + w*16 + m;
            #pragma unroll
            for (int r=0;r<4;r++) op[(size_t)r*EE] = acc[r] + bias[i];
        }
    }
}

// ---------------- output projection: weights in registers, stream A ----------------
// Block = 512 thr = 8 waves. Wave w -> cols [w*16, w*16+16) of Wo. A = attn out
// (bf16 hi/lo in ws), double-buffered.
__global__ void __launch_bounds__(512,2) gemm_o(const unsigned short* __restrict__ ah,
        const unsigned short* __restrict__ al,
        const unsigned short* __restrict__ WHg, const unsigned short* __restrict__ WLg,
        const float* __restrict__ bo, float* __restrict__ out)
{
    const int w = threadIdx.x >> 6;
    const int lane = threadIdx.x & 63;
    const int m = lane & 15, g = lane >> 4;
    const int rowB = blockIdx.x * (16*RT);

    bf16x8 bH[4], bL[4];
    {
        const unsigned short* WHp = WHg + (size_t)(w*16 + m)*EE;
        const unsigned short* WLp = WLg + (size_t)(w*16 + m)*EE;
        #pragma unroll
        for (int kc=0;kc<4;kc++){
            bH[kc] = ld_bf8(WHp + kc*32 + g*8);
            bL[kc] = ld_bf8(WLp + kc*32 + g*8);
        }
    }
    const float biasv = bo[w*16+m];

    bf16x8 fa[2][8];                            // [buf][kc] = hi, [buf][4+kc] = lo
    {
        const size_t abase = (size_t)(rowB + m) * EE;
        #pragma unroll
        for (int kc=0;kc<4;kc++){
            fa[0][kc]   = ld_bf8(ah + abase + kc*32 + g*8);
            fa[0][4+kc] = ld_bf8(al + abase + kc*32 + g*8);
        }
    }
    #pragma unroll
    for (int rt=0; rt<RT; rt++){
        const int row0 = rowB + rt*16;
        if (rt+1 < RT){
            const size_t abase = (size_t)(row0 + 16 + m) * EE;
            #pragma unroll
            for (int kc=0;kc<4;kc++){
                fa[(rt+1)&1][kc]   = ld_bf8(ah + abase + kc*32 + g*8);
                fa[(rt+1)&1][4+kc] = ld_bf8(al + abase + kc*32 + g*8);
            }
        }
        f32x4 acc = {0.f,0.f,0.f,0.f};
        #pragma unroll
        for (int kc=0;kc<4;kc++){
            acc = __builtin_amdgcn_mfma_f32_16x16x32_bf16(fa[rt&1][kc],   bH[kc], acc, 0,0,0);
            acc = __builtin_amdgcn_mfma_f32_16x16x32_bf16(fa[rt&1][kc],   bL[kc], acc, 0,0,0);
            acc = __builtin_amdgcn_mfma_f32_16x16x32_bf16(fa[rt&1][4+kc], bH[kc], acc, 0,0,0);
        }
        float* op = out + (size_t)(row0 + g*4)*EE + w*16 + m;
        #pragma unroll
        for (int r=0;r<4;r++) op[(size_t)r*EE] = acc[r] + biasv;
    }
}

// ---------------- sliding-window attention, fp32 exact ----------------
// 4 threads per position (each owns 8 of D=32). Block = 256 thr = 64 positions
// of one (b,h). LDS: K/V 96-row halo stride 33 + probs staging. ~33 KB.
// ALL sc[] indexing is compile-time (rule #20: runtime index -> scratch spill).
__global__ void __launch_bounds__(256) attn_kernel(const float* __restrict__ Qf,
        const float* __restrict__ Kf, const float* __restrict__ Vf,
        float* __restrict__ probs, unsigned short* __restrict__ ah, unsigned short* __restrict__ al)
{
    __shared__ float Kl[96*33];
    __shared__ float Vl[96*33];
    __shared__ float Pl[64*WW];                // probs staging, 64 rows x 33
    const int t = threadIdx.x;
    const int bh = blockIdx.y;
    const int b = bh >> 2, h = bh & 3;
    const int n0 = blockIdx.x * 64;
    const size_t rowbase = (size_t)b * NN;

    // stage K/V rows [n0-16, n0+80) slice [h*32, h*32+32), zero-fill OOB
    #pragma unroll
    for (int i=0;i<3;i++){
        int idx = t + i*256;                   // 0..767
        int row = idx >> 3, q4 = idx & 7;
        int grow = n0 - 16 + row;
        float4 kv = make_float4(0.f,0.f,0.f,0.f);
        float4 vv = make_float4(0.f,0.f,0.f,0.f);
        if (grow >= 0 && grow < NN){
            size_t goff = (rowbase + grow)*EE + h*DD + q4*4;
            kv = *(const float4*)(Kf + goff);
            vv = *(const float4*)(Vf + goff);
        }
        int lo = row*33 + q4*4;
        *(float4*)(Kl + lo) = kv;
        *(float4*)(Vl + lo) = vv;
    }
    __syncthreads();

    const int p = t >> 2, e = t & 3;           // position p, dim-quarter e
    const int n = n0 + p;

    float qr[8];
    {
        const float4* qp = (const float4*)(Qf + (rowbase + n)*EE + h*DD + e*8);
        float4 v0 = qp[0], v1 = qp[1];
        qr[0]=v0.x; qr[1]=v0.y; qr[2]=v0.z; qr[3]=v0.w;
        qr[4]=v1.x; qr[5]=v1.y; qr[6]=v1.z; qr[7]=v1.w;
    }

    float sc[WW];
    #pragma unroll
    for (int w=0; w<WW; w++){
        const float* kr = &Kl[(p+w)*33 + e*8];
        float s = 0.f;
        #pragma unroll
        for (int k=0;k<8;k++) s = fmaf(qr[k], kr[k], s);
        sc[w] = s;
    }
    // quad-reduce: all 4 threads end with the full dot product
    #pragma unroll
    for (int w=0; w<WW; w++){
        float s = sc[w];
        s += __shfl_xor(s, 1);
        s += __shfl_xor(s, 2);
        sc[w] = s * 0.17677669529663687f;      // 1/sqrt(32)
    }

    float mx = sc[0];
    #pragma unroll
    for (int w=1;w<WW;w++) mx = fmaxf(mx, sc[w]);
    float sum = 0.f;
    #pragma unroll
    for (int w=0;w<WW;w++){ sc[w] = __expf(sc[w]-mx); sum += sc[w]; }
    float inv = 1.f / sum;
    #pragma unroll
    for (int w=0;w<WW;w++) sc[w] *= inv;

    // probs -> LDS staging; quad splits 9+8+8+8, every sc[] index compile-time
    {
        float* pl = Pl + p*WW;
        if (e==0){
            #pragma unroll
            for (int w=0;w<9;w++) pl[w] = sc[w];
        } else if (e==1){
            #pragma unroll
            for (int w=9;w<17;w++) pl[w] = sc[w];
        } else if (e==2){
            #pragma unroll
            for (int w=17;w<25;w++) pl[w] = sc[w];
        } else {
            #pragma unroll
            for (int w=25;w<WW;w++) pl[w] = sc[w];
        }
    }

    // PV over own 8 dims
    float acc[8];
    #pragma unroll
    for (int k=0;k<8;k++) acc[k]=0.f;
    #pragma unroll
    for (int w=0;w<WW;w++){
        const float* vr = &Vl[(p+w)*33 + e*8];
        float pw = sc[w];
        #pragma unroll
        for (int k=0;k<8;k++) acc[k] = fmaf(pw, vr[k], acc[k]);
    }

    unsigned short hi[8], lo2[8];
    #pragma unroll
    for (int k=0;k<8;k++){ hi[k]=f2bf(acc[k]); lo2[k]=f2bf(acc[k]-bf2f(hi[k])); }
    size_t aoff = (rowbase + n)*EE + h*DD + e*8;
    *(ushort4*)(ah + aoff)     = make_ushort4(hi[0],hi[1],hi[2],hi[3]);
    *(ushort4*)(ah + aoff + 4) = make_ushort4(hi[4],hi[5],hi[6],hi[7]);
    *(ushort4*)(al + aoff)     = make_ushort4(lo2[0],lo2[1],lo2[2],lo2[3]);
    *(ushort4*)(al + aoff + 4) = make_ushort4(lo2[4],lo2[5],lo2[6],lo2[7]);

    // coalesced probs flush: block's region is 64*33 = 2112 contiguous floats
    __syncthreads();
    float* pbase = probs + ((size_t)bh*NN + n0)*WW;
    #pragma unroll
    for (int i=0;i<9;i++){
        int idx = t + i*256;
        if (idx < 64*WW) pbase[idx] = Pl[idx];
    }
}

extern "C" void kernel_launch(void* const* d_in, const int* in_sizes, int n_in,
                              void* d_out, int out_size, void* d_ws, size_t ws_size,
                              hipStream_t stream) {
    const float* q  = (const float*)d_in[0];
    const float* Wq = (const float*)d_in[1];  const float* bq = (const float*)d_in[2];
    const float* Wk = (const float*)d_in[3];  const float* bk = (const float*)d_in[4];
    const float* Wv = (const float*)d_in[5];  const float* bv = (const float*)d_in[6];
    const float* Wo = (const float*)d_in[7];  const float* bo = (const float*)d_in[8];

    float* out   = (float*)d_out;             // (B,N,E) = 4194304 floats
    float* probs = out + QELEMS;              // (B,H,N,W) = 4325376 floats

    // workspace carve (~67 MB)
    unsigned short* a_hi = (unsigned short*)d_ws;
    unsigned short* a_lo = a_hi + QELEMS;
    unsigned short* w_hi = a_lo + QELEMS;
    unsigned short* w_lo = w_hi + 4*WELEMS;
    float* Qf = (float*)(w_lo + 4*WELEMS);
    float* Kf = Qf + QELEMS;
    float* Vf = Kf + QELEMS;

    prep_w<<<4*WELEMS/256, 256, 0, stream>>>(Wq, Wk, Wv, Wo, w_hi, w_lo);
    gemm_qkv<<<dim3(MROWS/(16*RT), 1), 512, 0, stream>>>(q, w_hi, w_lo,
                                                         bq, bk, bv, Qf, Kf, Vf);
    attn_kernel<<<dim3(NN/64, BN*HH), 256, 0, stream>>>(Qf, Kf, Vf, probs, a_hi, a_lo);
    gemm_o<<<dim3(MROWS/(16*RT), 1), 512, 0, stream>>>(a_hi, a_lo,
                                                       w_hi + 3*WELEMS, w_lo + 3*WELEMS, bo, out);
}